// Round 1
// baseline (52.238 us; speedup 1.0000x reference)
//
#include <hip/hip_runtime.h>

// SIR RK4 integrator: B=65536 systems, 200 time points, out (B,200,3) f32.
// One thread per system. Writes buffered 4 steps -> 3x float4 stores (16B aligned:
// row stride 2400B, group stride 48B).

__global__ __launch_bounds__(256) void sir_rk4_kernel(
    const float* __restrict__ params, float* __restrict__ out, int B)
{
    const int b = blockIdx.x * 256 + threadIdx.x;
    if (b >= B) return;

    const float4 p = reinterpret_cast<const float4*>(params)[b];
    const float beta = p.x, gamma = p.y;
    float S = p.z, I = p.w;
    float R = 1.0f - S - I;

    const float dt = 100.0f / 199.0f;   // T_POINTS spacing (f32 linspace diffs are within 1 ulp)
    const float h2 = 0.5f * dt;
    const float h6 = dt / 6.0f;

    float4* __restrict__ o4 = reinterpret_cast<float4*>(out + (size_t)b * 600);

    auto step = [&]() {
        // k1
        float bSI1 = beta * S * I;
        float gI1  = gamma * I;
        float k1S = -bSI1, k1I = bSI1 - gI1, k1R = gI1;
        // k2 at y + h2*k1 (rhs only reads S,I)
        float S2 = __builtin_fmaf(h2, k1S, S);
        float I2 = __builtin_fmaf(h2, k1I, I);
        float bSI2 = beta * S2 * I2;
        float gI2  = gamma * I2;
        float k2S = -bSI2, k2I = bSI2 - gI2, k2R = gI2;
        // k3 at y + h2*k2
        float S3 = __builtin_fmaf(h2, k2S, S);
        float I3 = __builtin_fmaf(h2, k2I, I);
        float bSI3 = beta * S3 * I3;
        float gI3  = gamma * I3;
        float k3S = -bSI3, k3I = bSI3 - gI3, k3R = gI3;
        // k4 at y + dt*k3
        float S4 = __builtin_fmaf(dt, k3S, S);
        float I4 = __builtin_fmaf(dt, k3I, I);
        float bSI4 = beta * S4 * I4;
        float gI4  = gamma * I4;
        float k4S = -bSI4, k4I = bSI4 - gI4, k4R = gI4;
        // y += dt/6 * (k1 + 2*k2 + 2*k3 + k4)
        S = __builtin_fmaf(h6, k1S + 2.0f * (k2S + k3S) + k4S, S);
        I = __builtin_fmaf(h6, k1I + 2.0f * (k2I + k3I) + k4I, I);
        R = __builtin_fmaf(h6, k1R + 2.0f * (k2R + k3R) + k4R, R);
    };

    // 50 groups of 4 time points each; group 0 starts with the initial state.
    for (int g = 0; g < 50; ++g) {
        float4 va, vb, vc;
        if (g == 0) { va.x = S; va.y = I; va.z = R; }
        else        { step(); va.x = S; va.y = I; va.z = R; }
        step(); va.w = S; vb.x = I; vb.y = R;
        step(); vb.z = S; vb.w = I; vc.x = R;
        step(); vc.y = S; vc.z = I; vc.w = R;
        o4[g * 3 + 0] = va;
        o4[g * 3 + 1] = vb;
        o4[g * 3 + 2] = vc;
    }
}

extern "C" void kernel_launch(void* const* d_in, const int* in_sizes, int n_in,
                              void* d_out, int out_size, void* d_ws, size_t ws_size,
                              hipStream_t stream) {
    const float* params = (const float*)d_in[0];
    float* out = (float*)d_out;
    const int B = in_sizes[0] / 4;                 // 65536
    const int grid = (B + 255) / 256;              // 256 blocks
    sir_rk4_kernel<<<grid, 256, 0, stream>>>(params, out, B);
}

// Round 2
// 36.098 us; speedup vs baseline: 1.4471x; 1.4471x over previous
//
#include <hip/hip_runtime.h>

// SIR RK4, B=65536 systems, 200 time points, out (B,200,3) f32 = 157.3 MB.
// Round 2: LDS-staged transposed flush for wave-coalesced full-line writes.
// 64 systems per 64-thread block (1 wave), 1024 blocks = 4 blocks/CU.
// Per chunk: integrate 40 points into LDS [64][124f], then flush with
// lane-consecutive float4 stores (contiguous 480B runs per row).

#define SYS_PER_BLK 64
#define ROW_F   124   // 40 pts * 3 floats = 120, +4 pad (31 float4: gcd(31,8)=1)
#define ROW_F4  31

__global__ __launch_bounds__(64) void sir_rk4_kernel(
    const float* __restrict__ params, float* __restrict__ out)
{
    const int t  = threadIdx.x;
    const int b0 = blockIdx.x * SYS_PER_BLK;
    const int b  = b0 + t;

    __shared__ float lbuf[SYS_PER_BLK * ROW_F];

    const float4 p = reinterpret_cast<const float4*>(params)[b];
    const float beta = p.x, gamma = p.y;
    float S = p.z, I = p.w;
    float R = 1.0f - S - I;

    const float dt = 100.0f / 199.0f;
    const float h2 = 0.5f * dt;
    const float h6 = dt / 6.0f;

    auto step = [&]() {
        float bSI1 = beta * S * I;
        float gI1  = gamma * I;
        float k1S = -bSI1, k1I = bSI1 - gI1, k1R = gI1;
        float S2 = __builtin_fmaf(h2, k1S, S);
        float I2 = __builtin_fmaf(h2, k1I, I);
        float bSI2 = beta * S2 * I2;
        float gI2  = gamma * I2;
        float k2S = -bSI2, k2I = bSI2 - gI2, k2R = gI2;
        float S3 = __builtin_fmaf(h2, k2S, S);
        float I3 = __builtin_fmaf(h2, k2I, I);
        float bSI3 = beta * S3 * I3;
        float gI3  = gamma * I3;
        float k3S = -bSI3, k3I = bSI3 - gI3, k3R = gI3;
        float S4 = __builtin_fmaf(dt, k3S, S);
        float I4 = __builtin_fmaf(dt, k3I, I);
        float bSI4 = beta * S4 * I4;
        float gI4  = gamma * I4;
        float k4S = -bSI4, k4I = bSI4 - gI4, k4R = gI4;
        S = __builtin_fmaf(h6, k1S + 2.0f * (k2S + k3S) + k4S, S);
        I = __builtin_fmaf(h6, k1I + 2.0f * (k2I + k3I) + k4I, I);
        R = __builtin_fmaf(h6, k1R + 2.0f * (k2R + k3R) + k4R, R);
    };

    float4* lrow  = reinterpret_cast<float4*>(&lbuf[t * ROW_F]);
    const float4* lall = reinterpret_cast<const float4*>(lbuf);
    float4* gout  = reinterpret_cast<float4*>(out) + (size_t)b0 * 150;  // 600 f/row

    for (int c = 0; c < 5; ++c) {
        // integrate 40 points (10 groups of 4) into this thread's LDS row
        #pragma unroll
        for (int g = 0; g < 10; ++g) {
            float4 va, vb, vc;
            if (c == 0 && g == 0) { va.x = S; va.y = I; va.z = R; }
            else                  { step(); va.x = S; va.y = I; va.z = R; }
            step(); va.w = S; vb.x = I; vb.y = R;
            step(); vb.z = S; vb.w = I; vc.x = R;
            step(); vc.y = S; vc.z = I; vc.w = R;
            lrow[g * 3 + 0] = va;
            lrow[g * 3 + 1] = vb;
            lrow[g * 3 + 2] = vc;
        }
        __syncthreads();
        // coalesced flush: 64 rows x 30 float4 (480B/row) = 1920 float4, 30 iters
        #pragma unroll 6
        for (int it = 0; it < 30; ++it) {
            int f = it * 64 + t;
            int r = f / 30;
            int q = f - r * 30;
            float4 v = lall[r * ROW_F4 + q];
            gout[(size_t)r * 150 + c * 30 + q] = v;
        }
        __syncthreads();
    }
}

extern "C" void kernel_launch(void* const* d_in, const int* in_sizes, int n_in,
                              void* d_out, int out_size, void* d_ws, size_t ws_size,
                              hipStream_t stream) {
    const float* params = (const float*)d_in[0];
    float* out = (float*)d_out;
    const int B = in_sizes[0] / 4;                 // 65536
    const int grid = B / SYS_PER_BLK;              // 1024 blocks
    sir_rk4_kernel<<<grid, SYS_PER_BLK, 0, stream>>>(params, out);
}